// Round 1
// baseline (635.064 us; speedup 1.0000x reference)
//
#include <hip/hip_runtime.h>
#include <cmath>

#define NC 192   // H*C
#define CC 64
#define DOUTK 16

__device__ __forceinline__ float lrelu(float x) { return x > 0.f ? x : 0.2f * x; }

// ---------------- CSR build (dst-sorted, self-loops handled implicitly) ----------------
__global__ void k_hist(const int* __restrict__ dsts, int* __restrict__ deg, int E) {
  int e = blockIdx.x * 256 + threadIdx.x;
  if (e < E) atomicAdd(&deg[dsts[e]], 1);
}

__global__ void k_scan_block(const int* __restrict__ deg, int* __restrict__ rowptr,
                             int* __restrict__ bsum, int Nn) {
  __shared__ int tmp[256];
  int i = blockIdx.x * 256 + threadIdx.x;
  int v = (i < Nn) ? deg[i] : 0;
  tmp[threadIdx.x] = v;
  __syncthreads();
  for (int off = 1; off < 256; off <<= 1) {
    int t = (threadIdx.x >= off) ? tmp[threadIdx.x - off] : 0;
    __syncthreads();
    tmp[threadIdx.x] += t;
    __syncthreads();
  }
  if (i < Nn) rowptr[i] = tmp[threadIdx.x] - v;   // exclusive
  if (threadIdx.x == 255) bsum[blockIdx.x] = tmp[255];
}

__global__ void k_scan_bsum(int* __restrict__ bsum, int B) {
  __shared__ int tmp[256];
  int v = (threadIdx.x < B) ? bsum[threadIdx.x] : 0;
  tmp[threadIdx.x] = v;
  __syncthreads();
  for (int off = 1; off < 256; off <<= 1) {
    int t = (threadIdx.x >= off) ? tmp[threadIdx.x - off] : 0;
    __syncthreads();
    tmp[threadIdx.x] += t;
    __syncthreads();
  }
  if (threadIdx.x < B) bsum[threadIdx.x] = tmp[threadIdx.x] - v;  // exclusive
}

__global__ void k_add_off(int* __restrict__ rowptr, const int* __restrict__ bsum,
                          int* __restrict__ cursor, int Nn) {
  int i = blockIdx.x * 256 + threadIdx.x;
  if (i < Nn) {
    int r = rowptr[i] + bsum[blockIdx.x];
    rowptr[i] = r;
    cursor[i] = r;
  }
}

__global__ void k_scatter(const int* __restrict__ srcs, const int* __restrict__ dsts,
                          int* __restrict__ cursor, int* __restrict__ csr_src, int E) {
  int e = blockIdx.x * 256 + threadIdx.x;
  if (e < E) {
    int d = dsts[e];
    int p = atomicAdd(&cursor[d], 1);
    csr_src[p] = srcs[e];
  }
}

// ---------------- GEMM: XW[M,192] = X[M,K] @ W[K,192] (fp32 vector) ----------------
template<int K>
__global__ void k_gemm(const float* __restrict__ X, const float* __restrict__ W,
                       float* __restrict__ XW, int M) {
  __shared__ float xs[16][K];
  int r0 = blockIdx.x * 16;
  int col = threadIdx.x;  // 0..191
  for (int idx = threadIdx.x; idx < 16 * K; idx += 192) {
    int r = idx / K, k = idx - r * K;
    xs[r][k] = (r0 + r < M) ? X[(size_t)(r0 + r) * K + k] : 0.f;
  }
  __syncthreads();
  float acc[16];
#pragma unroll
  for (int r = 0; r < 16; ++r) acc[r] = 0.f;
  for (int k = 0; k < K; ++k) {
    float w = W[k * NC + col];
#pragma unroll
    for (int r = 0; r < 16; ++r) acc[r] += xs[r][k] * w;  // xs broadcast read
  }
#pragma unroll
  for (int r = 0; r < 16; ++r)
    if (r0 + r < M) XW[(size_t)(r0 + r) * NC + col] = acc[r];
}

// ---------------- per-node attention score vectors a_src/a_dst [N,3] ----------------
__global__ void k_att(const float* __restrict__ xw, const float* __restrict__ att_src,
                      const float* __restrict__ att_dst, float* __restrict__ asrc,
                      float* __restrict__ adst, int Nn) {
  int n = blockIdx.x;
  int h = threadIdx.x >> 6, lane = threadIdx.x & 63;
  float v = xw[(size_t)n * NC + h * 64 + lane];
  float s1 = v * att_src[h * 64 + lane];
  float s2 = v * att_dst[h * 64 + lane];
#pragma unroll
  for (int off = 32; off; off >>= 1) {
    s1 += __shfl_xor(s1, off);
    s2 += __shfl_xor(s2, off);
  }
  if (lane == 0) {
    asrc[n * 3 + h] = s1;
    adst[n * 3 + h] = s2;
  }
}

// ---------------- fused segment-softmax + aggregation, one wave per node ----------------
template<bool RELU>
__global__ void k_aggregate(const float* __restrict__ xw, const float* __restrict__ asrc,
                            const float* __restrict__ adst, const int* __restrict__ rowptr,
                            const int* __restrict__ deg, const int* __restrict__ csr_src,
                            const float* __restrict__ bias, float* __restrict__ out, int Nn) {
  int wid = threadIdx.x >> 6, lane = threadIdx.x & 63;
  int n = blockIdx.x * 4 + wid;
  if (n >= Nn) return;
  int row = rowptr[n], d = deg[n];
  float ad0 = adst[n * 3], ad1 = adst[n * 3 + 1], ad2 = adst[n * 3 + 2];
  float sa0 = lrelu(asrc[n * 3] + ad0);       // self-loop alpha (PyG adds self-loops)
  float sa1 = lrelu(asrc[n * 3 + 1] + ad1);
  float sa2 = lrelu(asrc[n * 3 + 2] + ad2);
  float m0 = sa0, m1 = sa1, m2 = sa2;
  // pass 1: max over incoming edges (lanes strided over edges)
  for (int e = lane; e < d; e += 64) {
    int s = csr_src[row + e];
    m0 = fmaxf(m0, lrelu(asrc[s * 3] + ad0));
    m1 = fmaxf(m1, lrelu(asrc[s * 3 + 1] + ad1));
    m2 = fmaxf(m2, lrelu(asrc[s * 3 + 2] + ad2));
  }
#pragma unroll
  for (int off = 32; off; off >>= 1) {
    m0 = fmaxf(m0, __shfl_xor(m0, off));
    m1 = fmaxf(m1, __shfl_xor(m1, off));
    m2 = fmaxf(m2, __shfl_xor(m2, off));
  }
  // pass 1b: sum of exp
  float p0 = 0.f, p1 = 0.f, p2 = 0.f;
  for (int e = lane; e < d; e += 64) {
    int s = csr_src[row + e];
    p0 += __expf(lrelu(asrc[s * 3] + ad0) - m0);
    p1 += __expf(lrelu(asrc[s * 3 + 1] + ad1) - m1);
    p2 += __expf(lrelu(asrc[s * 3 + 2] + ad2) - m2);
  }
#pragma unroll
  for (int off = 32; off; off >>= 1) {
    p0 += __shfl_xor(p0, off);
    p1 += __shfl_xor(p1, off);
    p2 += __shfl_xor(p2, off);
  }
  float S0 = p0 + __expf(sa0 - m0) + 1e-16f;
  float S1 = p1 + __expf(sa1 - m1) + 1e-16f;
  float S2 = p2 + __expf(sa2 - m2) + 1e-16f;
  // pass 2: weighted gather; lane = channel, edges sequential (coalesced 768B/edge)
  float acc0 = 0.f, acc1 = 0.f, acc2 = 0.f;
  for (int e = 0; e < d; ++e) {
    int s = csr_src[row + e];
    float w0 = __expf(lrelu(asrc[s * 3] + ad0) - m0);
    float w1 = __expf(lrelu(asrc[s * 3 + 1] + ad1) - m1);
    float w2 = __expf(lrelu(asrc[s * 3 + 2] + ad2) - m2);
    const float* xr = xw + (size_t)s * NC;
    acc0 += w0 * xr[lane];
    acc1 += w1 * xr[64 + lane];
    acc2 += w2 * xr[128 + lane];
  }
  const float* xrs = xw + (size_t)n * NC;
  acc0 += __expf(sa0 - m0) * xrs[lane];
  acc1 += __expf(sa1 - m1) * xrs[64 + lane];
  acc2 += __expf(sa2 - m2) * xrs[128 + lane];
  float o = (acc0 / S0 + acc1 / S1 + acc2 / S2) * (1.f / 3.f) + bias[lane];
  out[(size_t)n * CC + lane] = RELU ? fmaxf(o, 0.f) : o;
}

// ---------------- final linear: logit[N,16] = h[N,64] @ Wl[64,16] + bl ----------------
__global__ void k_logit(const float* __restrict__ h, const float* __restrict__ Wl,
                        const float* __restrict__ bl, float* __restrict__ out, int Nn) {
  __shared__ float wl_s[CC * DOUTK];
  __shared__ float hrow[4][CC];
  int tid = threadIdx.x;
  for (int i = tid; i < CC * DOUTK; i += 256) wl_s[i] = Wl[i];
  int wid = tid >> 6, lane = tid & 63;
  int n = blockIdx.x * 4 + wid;
  if (n < Nn) hrow[wid][lane] = h[(size_t)n * CC + lane];
  __syncthreads();
  if (n < Nn && lane < DOUTK) {
    float acc = bl[lane];
#pragma unroll
    for (int c = 0; c < CC; ++c) acc += hrow[wid][c] * wl_s[c * DOUTK + lane];
    out[(size_t)n * DOUTK + lane] = acc;
  }
}

extern "C" void kernel_launch(void* const* d_in, const int* in_sizes, int n_in,
                              void* d_out, int out_size, void* d_ws, size_t ws_size,
                              hipStream_t stream) {
  const float* x   = (const float*)d_in[0];
  const float* W1  = (const float*)d_in[1];
  const float* as1 = (const float*)d_in[2];
  const float* ad1 = (const float*)d_in[3];
  const float* b1  = (const float*)d_in[4];
  const float* W2  = (const float*)d_in[5];
  const float* as2 = (const float*)d_in[6];
  const float* ad2 = (const float*)d_in[7];
  const float* b2  = (const float*)d_in[8];
  const float* Wl  = (const float*)d_in[9];
  const float* bl  = (const float*)d_in[10];
  const int* edges = (const int*)d_in[11];

  const int Nn = in_sizes[0] / 256;   // 50000
  const int E  = in_sizes[11] / 2;    // 800000
  const int* srcs = edges;
  const int* dsts = edges + E;

  float* out_logit = (float*)d_out;                       // [N,16]
  float* out_h     = (float*)d_out + (size_t)Nn * DOUTK;  // [N,64]

  char* p = (char*)d_ws;
  auto alloc = [&](size_t bytes) {
    char* r = p;
    p += (bytes + 255) & ~(size_t)255;
    return r;
  };
  float* xw    = (float*)alloc((size_t)Nn * NC * 4);
  float* h1    = (float*)alloc((size_t)Nn * CC * 4);
  float* asrc  = (float*)alloc((size_t)Nn * 3 * 4);
  float* adst  = (float*)alloc((size_t)Nn * 3 * 4);
  int* deg     = (int*)alloc((size_t)Nn * 4);
  int* rowptr  = (int*)alloc((size_t)Nn * 4);
  int* cursor  = (int*)alloc((size_t)Nn * 4);
  int* bsum    = (int*)alloc(256 * 4);
  int* csr_src = (int*)alloc((size_t)E * 4);

  const int nB = (Nn + 255) / 256;   // 196 (<=256 required by k_scan_bsum)
  const int eB = (E + 255) / 256;
  const int gB = (Nn + 15) / 16;
  const int aB = (Nn + 3) / 4;

  // CSR build (ws is re-poisoned every call -> rebuild everything)
  hipMemsetAsync(deg, 0, (size_t)Nn * 4, stream);
  k_hist<<<eB, 256, 0, stream>>>(dsts, deg, E);
  k_scan_block<<<nB, 256, 0, stream>>>(deg, rowptr, bsum, Nn);
  k_scan_bsum<<<1, 256, 0, stream>>>(bsum, nB);
  k_add_off<<<nB, 256, 0, stream>>>(rowptr, bsum, cursor, Nn);
  k_scatter<<<eB, 256, 0, stream>>>(srcs, dsts, cursor, csr_src, E);

  // layer 1
  k_gemm<256><<<gB, 192, 0, stream>>>(x, W1, xw, Nn);
  k_att<<<Nn, 192, 0, stream>>>(xw, as1, ad1, asrc, adst, Nn);
  k_aggregate<true><<<aB, 256, 0, stream>>>(xw, asrc, adst, rowptr, deg, csr_src, b1, h1, Nn);

  // layer 2
  k_gemm<64><<<gB, 192, 0, stream>>>(h1, W2, xw, Nn);
  k_att<<<Nn, 192, 0, stream>>>(xw, as2, ad2, asrc, adst, Nn);
  k_aggregate<false><<<aB, 256, 0, stream>>>(xw, asrc, adst, rowptr, deg, csr_src, b2, out_h, Nn);

  // final linear
  k_logit<<<aB, 256, 0, stream>>>(out_h, Wl, bl, out_logit, Nn);
}

// Round 2
// 549.281 us; speedup vs baseline: 1.1562x; 1.1562x over previous
//
#include <hip/hip_runtime.h>
#include <cmath>

#define NC 192   // H*C
#define CC 64
#define DOUTK 16

__device__ __forceinline__ float lrelu(float x) { return x > 0.f ? x : 0.2f * x; }

__device__ __forceinline__ float wred_sum(float v) {
#pragma unroll
  for (int off = 32; off; off >>= 1) v += __shfl_xor(v, off);
  return v;
}
__device__ __forceinline__ float wred_max(float v) {
#pragma unroll
  for (int off = 32; off; off >>= 1) v = fmaxf(v, __shfl_xor(v, off));
  return v;
}

// ---------------- CSR build (dst-sorted) ----------------
__global__ void k_hist(const int* __restrict__ dsts, int* __restrict__ deg, int E) {
  int e = blockIdx.x * 256 + threadIdx.x;
  if (e < E) atomicAdd(&deg[dsts[e]], 1);
}

__global__ void k_scan_block(const int* __restrict__ deg, int* __restrict__ rowptr,
                             int* __restrict__ bsum, int Nn) {
  __shared__ int tmp[256];
  int i = blockIdx.x * 256 + threadIdx.x;
  int v = (i < Nn) ? deg[i] : 0;
  tmp[threadIdx.x] = v;
  __syncthreads();
  for (int off = 1; off < 256; off <<= 1) {
    int t = (threadIdx.x >= off) ? tmp[threadIdx.x - off] : 0;
    __syncthreads();
    tmp[threadIdx.x] += t;
    __syncthreads();
  }
  if (i < Nn) rowptr[i] = tmp[threadIdx.x] - v;   // exclusive
  if (threadIdx.x == 255) bsum[blockIdx.x] = tmp[255];
}

__global__ void k_scan_bsum(int* __restrict__ bsum, int B) {
  __shared__ int tmp[256];
  int v = (threadIdx.x < B) ? bsum[threadIdx.x] : 0;
  tmp[threadIdx.x] = v;
  __syncthreads();
  for (int off = 1; off < 256; off <<= 1) {
    int t = (threadIdx.x >= off) ? tmp[threadIdx.x - off] : 0;
    __syncthreads();
    tmp[threadIdx.x] += t;
    __syncthreads();
  }
  if (threadIdx.x < B) bsum[threadIdx.x] = tmp[threadIdx.x] - v;  // exclusive
}

__global__ void k_add_off(int* __restrict__ rowptr, const int* __restrict__ bsum,
                          int* __restrict__ cursor, int Nn) {
  int i = blockIdx.x * 256 + threadIdx.x;
  if (i < Nn) {
    int r = rowptr[i] + bsum[blockIdx.x];
    rowptr[i] = r;
    cursor[i] = r;
  }
}

__global__ void k_scatter(const int* __restrict__ srcs, const int* __restrict__ dsts,
                          int* __restrict__ cursor, int* __restrict__ csr_src, int E) {
  int e = blockIdx.x * 256 + threadIdx.x;
  if (e < E) {
    int d = dsts[e];
    int p = atomicAdd(&cursor[d], 1);
    csr_src[p] = srcs[e];
  }
}

// ---------------- GEMM + fused attention scores ----------------
// XW[M,192] = X[M,K] @ W[K,192]; asrc/adst[M,3] = rowwise dots with att vectors.
// Block: 256 thr = 4 waves; tile 32 rows. Wave tr owns rows tr*8..tr*8+7; lane tc owns
// cols {tc, 64+tc, 128+tc}. xs reads are wave-uniform ds_read_b128 broadcasts (4 k/read),
// W reads are coalesced L2-resident dwords. 96 FMA per 4-k chunk per lane -> FMA-bound.
template<int K>
__global__ __launch_bounds__(256) void k_gemm_att(
    const float* __restrict__ X, const float* __restrict__ W,
    const float* __restrict__ att_src, const float* __restrict__ att_dst,
    float* __restrict__ XW, float* __restrict__ asrc, float* __restrict__ adst, int M) {
  __shared__ float xs[32][K];
  const int tid = threadIdx.x;
  const int tr = tid >> 6;      // wave 0..3
  const int tc = tid & 63;      // lane
  const int r0 = blockIdx.x * 32;

  // stage X tile, float4-coalesced, zero-pad tail rows
  const int nf4 = 32 * (K / 4);
  for (int i = tid; i < nf4; i += 256) {
    int r = i / (K / 4), c4 = i % (K / 4);
    float4 v = make_float4(0.f, 0.f, 0.f, 0.f);
    if (r0 + r < M) v = ((const float4*)X)[(size_t)(r0 + r) * (K / 4) + c4];
    *(float4*)&xs[r][c4 * 4] = v;
  }
  __syncthreads();

  float acc[8][3];
#pragma unroll
  for (int r = 0; r < 8; ++r)
#pragma unroll
    for (int h = 0; h < 3; ++h) acc[r][h] = 0.f;

  const int rw = tr * 8;
  for (int kk = 0; kk < K; kk += 4) {
    float4 xv[8];
#pragma unroll
    for (int r = 0; r < 8; ++r) xv[r] = *(const float4*)&xs[rw + r][kk];
    float w[4][3];
#pragma unroll
    for (int j = 0; j < 4; ++j)
#pragma unroll
      for (int h = 0; h < 3; ++h) w[j][h] = W[(size_t)(kk + j) * NC + h * 64 + tc];
#pragma unroll
    for (int r = 0; r < 8; ++r)
#pragma unroll
      for (int h = 0; h < 3; ++h)
        acc[r][h] += xv[r].x * w[0][h] + xv[r].y * w[1][h] +
                     xv[r].z * w[2][h] + xv[r].w * w[3][h];
  }

  // epilogue: store XW + fused attention score reduction
  float avs[3], avd[3];
#pragma unroll
  for (int h = 0; h < 3; ++h) {
    avs[h] = att_src[h * 64 + tc];
    avd[h] = att_dst[h * 64 + tc];
  }
#pragma unroll
  for (int r = 0; r < 8; ++r) {
    int row = r0 + rw + r;
    if (row >= M) break;
    float s0 = wred_sum(acc[r][0] * avs[0]);
    float s1 = wred_sum(acc[r][1] * avs[1]);
    float s2 = wred_sum(acc[r][2] * avs[2]);
    float d0 = wred_sum(acc[r][0] * avd[0]);
    float d1 = wred_sum(acc[r][1] * avd[1]);
    float d2 = wred_sum(acc[r][2] * avd[2]);
#pragma unroll
    for (int h = 0; h < 3; ++h) XW[(size_t)row * NC + h * 64 + tc] = acc[r][h];
    if (tc == 0) {
      asrc[row * 3 + 0] = s0; asrc[row * 3 + 1] = s1; asrc[row * 3 + 2] = s2;
      adst[row * 3 + 0] = d0; adst[row * 3 + 1] = d1; adst[row * 3 + 2] = d2;
    }
  }
}

// ---------------- fused segment-softmax + aggregation, one wave per node ----------------
template<bool RELU>
__global__ __launch_bounds__(256) void k_aggregate(
    const float* __restrict__ xw, const float* __restrict__ asrc,
    const float* __restrict__ adst, const int* __restrict__ rowptr,
    const int* __restrict__ deg, const int* __restrict__ csr_src,
    const float* __restrict__ bias, float* __restrict__ out, int Nn) {
  int wid = threadIdx.x >> 6, lane = threadIdx.x & 63;
  int n = blockIdx.x * 4 + wid;
  if (n >= Nn) return;
  int row = rowptr[n], d = deg[n];
  float ad0 = adst[n * 3], ad1 = adst[n * 3 + 1], ad2 = adst[n * 3 + 2];
  float sa0 = lrelu(asrc[n * 3] + ad0);       // self-loop alpha
  float sa1 = lrelu(asrc[n * 3 + 1] + ad1);
  float sa2 = lrelu(asrc[n * 3 + 2] + ad2);

  float acc0, acc1, acc2, S0, S1, S2;

  if (d <= 64) {
    // fast path: lane e owns edge e; alpha computed exactly once per edge
    int s = 0;
    float al0 = -INFINITY, al1 = -INFINITY, al2 = -INFINITY;
    if (lane < d) {
      s = csr_src[row + lane];
      al0 = lrelu(asrc[s * 3] + ad0);
      al1 = lrelu(asrc[s * 3 + 1] + ad1);
      al2 = lrelu(asrc[s * 3 + 2] + ad2);
    }
    float m0 = fmaxf(wred_max(al0), sa0);
    float m1 = fmaxf(wred_max(al1), sa1);
    float m2 = fmaxf(wred_max(al2), sa2);
    float w0 = __expf(al0 - m0);   // inactive lanes: exp(-inf)=0
    float w1 = __expf(al1 - m1);
    float w2 = __expf(al2 - m2);
    float e0 = __expf(sa0 - m0), e1 = __expf(sa1 - m1), e2 = __expf(sa2 - m2);
    S0 = wred_sum(w0) + e0 + 1e-16f;
    S1 = wred_sum(w1) + e1 + 1e-16f;
    S2 = wred_sum(w2) + e2 + 1e-16f;
    // weighted gather: lane = channel, broadcast edge weight/src via shfl
    const float* xrs = xw + (size_t)n * NC;
    acc0 = e0 * xrs[lane];
    acc1 = e1 * xrs[64 + lane];
    acc2 = e2 * xrs[128 + lane];
    for (int e = 0; e < d; ++e) {
      int se = __shfl(s, e);
      float we0 = __shfl(w0, e), we1 = __shfl(w1, e), we2 = __shfl(w2, e);
      const float* xr = xw + (size_t)se * NC;
      acc0 += we0 * xr[lane];
      acc1 += we1 * xr[64 + lane];
      acc2 += we2 * xr[128 + lane];
    }
  } else {
    // slow path (d > 64): 3-pass, lane-strided
    float m0 = sa0, m1 = sa1, m2 = sa2;
    for (int e = lane; e < d; e += 64) {
      int s = csr_src[row + e];
      m0 = fmaxf(m0, lrelu(asrc[s * 3] + ad0));
      m1 = fmaxf(m1, lrelu(asrc[s * 3 + 1] + ad1));
      m2 = fmaxf(m2, lrelu(asrc[s * 3 + 2] + ad2));
    }
    m0 = wred_max(m0); m1 = wred_max(m1); m2 = wred_max(m2);
    float p0 = 0.f, p1 = 0.f, p2 = 0.f;
    for (int e = lane; e < d; e += 64) {
      int s = csr_src[row + e];
      p0 += __expf(lrelu(asrc[s * 3] + ad0) - m0);
      p1 += __expf(lrelu(asrc[s * 3 + 1] + ad1) - m1);
      p2 += __expf(lrelu(asrc[s * 3 + 2] + ad2) - m2);
    }
    S0 = wred_sum(p0) + __expf(sa0 - m0) + 1e-16f;
    S1 = wred_sum(p1) + __expf(sa1 - m1) + 1e-16f;
    S2 = wred_sum(p2) + __expf(sa2 - m2) + 1e-16f;
    const float* xrs = xw + (size_t)n * NC;
    acc0 = __expf(sa0 - m0) * xrs[lane];
    acc1 = __expf(sa1 - m1) * xrs[64 + lane];
    acc2 = __expf(sa2 - m2) * xrs[128 + lane];
    for (int e = 0; e < d; ++e) {
      int s = csr_src[row + e];
      float we0 = __expf(lrelu(asrc[s * 3] + ad0) - m0);
      float we1 = __expf(lrelu(asrc[s * 3 + 1] + ad1) - m1);
      float we2 = __expf(lrelu(asrc[s * 3 + 2] + ad2) - m2);
      const float* xr = xw + (size_t)s * NC;
      acc0 += we0 * xr[lane];
      acc1 += we1 * xr[64 + lane];
      acc2 += we2 * xr[128 + lane];
    }
  }

  float o = (acc0 / S0 + acc1 / S1 + acc2 / S2) * (1.f / 3.f) + bias[lane];
  out[(size_t)n * CC + lane] = RELU ? fmaxf(o, 0.f) : o;
}

// ---------------- final linear: logit[N,16] = h[N,64] @ Wl[64,16] + bl ----------------
__global__ void k_logit(const float* __restrict__ h, const float* __restrict__ Wl,
                        const float* __restrict__ bl, float* __restrict__ out, int Nn) {
  __shared__ float wl_s[CC * DOUTK];
  __shared__ float hrow[4][CC];
  int tid = threadIdx.x;
  for (int i = tid; i < CC * DOUTK; i += 256) wl_s[i] = Wl[i];
  int wid = tid >> 6, lane = tid & 63;
  int n = blockIdx.x * 4 + wid;
  if (n < Nn) hrow[wid][lane] = h[(size_t)n * CC + lane];
  __syncthreads();
  if (n < Nn && lane < DOUTK) {
    float acc = bl[lane];
#pragma unroll
    for (int c = 0; c < CC; ++c) acc += hrow[wid][c] * wl_s[c * DOUTK + lane];
    out[(size_t)n * DOUTK + lane] = acc;
  }
}

extern "C" void kernel_launch(void* const* d_in, const int* in_sizes, int n_in,
                              void* d_out, int out_size, void* d_ws, size_t ws_size,
                              hipStream_t stream) {
  const float* x   = (const float*)d_in[0];
  const float* W1  = (const float*)d_in[1];
  const float* as1 = (const float*)d_in[2];
  const float* ad1 = (const float*)d_in[3];
  const float* b1  = (const float*)d_in[4];
  const float* W2  = (const float*)d_in[5];
  const float* as2 = (const float*)d_in[6];
  const float* ad2 = (const float*)d_in[7];
  const float* b2  = (const float*)d_in[8];
  const float* Wl  = (const float*)d_in[9];
  const float* bl  = (const float*)d_in[10];
  const int* edges = (const int*)d_in[11];

  const int Nn = in_sizes[0] / 256;   // 50000
  const int E  = in_sizes[11] / 2;    // 800000
  const int* srcs = edges;
  const int* dsts = edges + E;

  float* out_logit = (float*)d_out;                       // [N,16]
  float* out_h     = (float*)d_out + (size_t)Nn * DOUTK;  // [N,64]

  char* p = (char*)d_ws;
  auto alloc = [&](size_t bytes) {
    char* r = p;
    p += (bytes + 255) & ~(size_t)255;
    return r;
  };
  float* xw    = (float*)alloc((size_t)Nn * NC * 4);
  float* h1    = (float*)alloc((size_t)Nn * CC * 4);
  float* asrc  = (float*)alloc((size_t)Nn * 3 * 4);
  float* adst  = (float*)alloc((size_t)Nn * 3 * 4);
  int* deg     = (int*)alloc((size_t)Nn * 4);
  int* rowptr  = (int*)alloc((size_t)Nn * 4);
  int* cursor  = (int*)alloc((size_t)Nn * 4);
  int* bsum    = (int*)alloc(256 * 4);
  int* csr_src = (int*)alloc((size_t)E * 4);

  const int nB = (Nn + 255) / 256;   // 196 (<=256 required by k_scan_bsum)
  const int eB = (E + 255) / 256;
  const int gB = (Nn + 31) / 32;
  const int aB = (Nn + 3) / 4;

  // CSR build (ws is re-poisoned every call -> rebuild everything)
  hipMemsetAsync(deg, 0, (size_t)Nn * 4, stream);
  k_hist<<<eB, 256, 0, stream>>>(dsts, deg, E);
  k_scan_block<<<nB, 256, 0, stream>>>(deg, rowptr, bsum, Nn);
  k_scan_bsum<<<1, 256, 0, stream>>>(bsum, nB);
  k_add_off<<<nB, 256, 0, stream>>>(rowptr, bsum, cursor, Nn);
  k_scatter<<<eB, 256, 0, stream>>>(srcs, dsts, cursor, csr_src, E);

  // layer 1 (att scores fused into GEMM epilogue)
  k_gemm_att<256><<<gB, 256, 0, stream>>>(x, W1, as1, ad1, xw, asrc, adst, Nn);
  k_aggregate<true><<<aB, 256, 0, stream>>>(xw, asrc, adst, rowptr, deg, csr_src, b1, h1, Nn);

  // layer 2
  k_gemm_att<64><<<gB, 256, 0, stream>>>(h1, W2, as2, ad2, xw, asrc, adst, Nn);
  k_aggregate<false><<<aB, 256, 0, stream>>>(xw, asrc, adst, rowptr, deg, csr_src, b2, out_h, Nn);

  // final linear
  k_logit<<<aB, 256, 0, stream>>>(out_h, Wl, bl, out_logit, Nn);
}